// Round 10
// baseline (26.919 us; speedup 1.0000x reference)
//
#include <hip/hip_runtime.h>
#include <hip/hip_bf16.h>

// Exact Gaussian lattice filter: out = (W - I) @ U, W_ij = exp(-0.5*max(d2,0))
// N=8192, D=5 features, C=21 channels.
//
// R10: R9's verified numerics (hi/lo bf16 S-MFMA for fi.fj, fp32 exponent,
// bf16 W@U MFMA, layouts m74/m101) + explicit 1-tile-ahead software pipeline:
// the next tile's 3 global b128 frag loads are issued BEFORE the current
// tile's S-MFMA/exp/MFMA body (R9 was latency-bound on the per-tile serial
// chain: ~600cyc chain vs ~180cyc issue x 4 waves/SIMD). Named register sets
// (no runtime-indexed arrays -> no scratch). Numerics byte-identical to R9.

#define NN 8192
#define CC 21
#define DD 5
#define NTILE_G (NN / 32)       // 256 j-tiles
#define ROWS 32                 // i-rows per block
#define NBLK (NN / ROWS)        // 256 blocks
#define MAINT 1024              // 16 waves
#define NWAVE 16
#define TPW (NTILE_G / NWAVE)   // 16 tiles per wave

#define F_OFF 0
#define U_OFF (NTILE_G * 64 * 16)   // 262144 B

typedef __attribute__((ext_vector_type(8)))  short    bf16x8;
typedef __attribute__((ext_vector_type(16))) float    f32x16;
typedef __attribute__((ext_vector_type(4)))  unsigned u32x4;

__device__ __forceinline__ short bf16s(float x) {
    __hip_bfloat16 h = __float2bfloat16(x);   // RNE, compiler-lowered
    short s; __builtin_memcpy(&s, &h, 2); return s;
}
__device__ __forceinline__ float bf16f(short s) {
    __hip_bfloat16 h; __builtin_memcpy(&h, &s, 2); return __bfloat162float(h);
}

// ---- pack kernel: F-frags then U-frags into ws ----
__global__ __launch_bounds__(256)
void pack_frags(const float* __restrict__ U, const float* __restrict__ ref,
                char* __restrict__ ws) {
    const int q = blockIdx.x * 256 + threadIdx.x;
    if (q < NTILE_G * 64) {
        // F-frag slot: tile = q>>6, frag-lane ln = q&63, j = tile*32 + (ln&31)
        const int tile = q >> 6, ln = q & 63;
        const int j = tile * 32 + (ln & 31);
        const float* fj = ref + (size_t)j * DD;
        short h_[5], l_[5];
        #pragma unroll
        for (int d = 0; d < DD; ++d) {
            const float f = fj[d];
            h_[d] = bf16s(f);
            l_[d] = bf16s(f - bf16f(h_[d]));
        }
        short v[8] __attribute__((aligned(16)));
        if (ln < 32) {
            v[0]=h_[0]; v[1]=h_[1]; v[2]=h_[2]; v[3]=h_[3];
            v[4]=h_[4]; v[5]=l_[0]; v[6]=l_[1]; v[7]=l_[2];
        } else {
            v[0]=l_[3]; v[1]=l_[4]; v[2]=h_[0]; v[3]=h_[1];
            v[4]=h_[2]; v[5]=h_[3]; v[6]=h_[4]; v[7]=0;
        }
        u32x4 pk; __builtin_memcpy(&pk, v, 16);
        *(u32x4*)(ws + F_OFF + (size_t)q * 16) = pk;
    } else {
        // U-frag slot: qu = q - 16384: tile=qu>>7, kt=(qu>>6)&1, ln=qu&63
        const int qu = q - NTILE_G * 64;
        const int ln = qu & 63, kt = (qu >> 6) & 1, tile = qu >> 7;
        const int c = ln & 31, g = ln >> 5;
        short v[8] __attribute__((aligned(16))) = {0,0,0,0,0,0,0,0};
        if (c < CC) {
            #pragma unroll
            for (int e = 0; e < 8; ++e) {
                const int j = tile * 32 + kt * 16 + (e & 3) + 8 * (e >> 2) + 4 * g;
                v[e] = bf16s(U[(size_t)j * CC + c]);
            }
        }
        u32x4 pk; __builtin_memcpy(&pk, v, 16);
        *(u32x4*)(ws + U_OFF + (size_t)qu * 16) = pk;
    }
}

// ---- main kernel ----
__global__ __launch_bounds__(MAINT, 4)
void lattice_main(const float* __restrict__ U, const float* __restrict__ ref,
                  const char* __restrict__ ws, float* __restrict__ out) {
    // LDS: [0,32768) aj[8192] during main loop; [0,65536) reduce buffer after
    __shared__ __align__(16) char smem[65536];
    float* ajb = (float*)smem;
    float* red = (float*)smem;   // [16][32][32] f32

    const int t    = threadIdx.x;
    const int lane = t & 63;
    const int wv   = t >> 6;        // wave 0..15
    const int h    = lane >> 5;
    const int m    = lane & 31;
    const int ibase = blockIdx.x * ROWS;
    const float L  = 1.4426950408889634f;    // log2(e)
    const float NH = -0.7213475204444817f;   // -0.5*log2(e)

    // ---- stage aj for ALL js (once per block) ----
    for (int j = t; j < NN; j += MAINT) {
        const float* fj = ref + (size_t)j * DD;
        const float f0 = fj[0], f1 = fj[1], f2 = fj[2], f3 = fj[3], f4 = fj[4];
        ajb[j] = NH * (f0*f0 + f1*f1 + f2*f2 + f3*f3 + f4*f4);
    }

    // ---- per-lane i-row: ai and L-scaled hi/lo B-fragment (same as R8/R9) ----
    const float* fiP = ref + (size_t)(ibase + m) * DD;
    const float fi0 = fiP[0], fi1 = fiP[1], fi2 = fiP[2], fi3 = fiP[3], fi4 = fiP[4];
    const float ai = NH * (fi0*fi0 + fi1*fi1 + fi2*fi2 + fi3*fi3 + fi4*fi4);
    bf16x8 bfi;
    {
        const float sf[5] = {L*fi0, L*fi1, L*fi2, L*fi3, L*fi4};
        short hi_[5], lo_[5];
        #pragma unroll
        for (int d = 0; d < DD; ++d) {
            hi_[d] = bf16s(sf[d]);
            lo_[d] = bf16s(sf[d] - bf16f(hi_[d]));
        }
        short bv[8] __attribute__((aligned(16)));
        bv[0] = h ? hi_[3] : hi_[0];
        bv[1] = h ? hi_[4] : hi_[1];
        bv[2] = h ? lo_[0] : hi_[2];
        bv[3] = h ? lo_[1] : hi_[3];
        bv[4] = h ? lo_[2] : hi_[4];
        bv[5] = h ? lo_[3] : hi_[0];
        bv[6] = h ? lo_[4] : hi_[1];
        bv[7] = h ? (short)0 : hi_[2];
        __builtin_memcpy(&bfi, bv, 16);
    }

    f32x16 acc;
    #pragma unroll
    for (int r = 0; r < 16; ++r) acc[r] = 0.f;

    __syncthreads();   // aj ready

    const char* Fws = ws + F_OFF;
    const char* Uws = ws + U_OFF;
    const int tile0 = wv * TPW;
    const int tmax  = tile0 + TPW - 1;

#define LOADF(TILE)  (*(const u32x4*)(Fws + ((size_t)((TILE) * 64 + lane)) * 16))
#define LOADB(TILE, KT) \
    (*(const u32x4*)(Uws + ((size_t)(((TILE) * 2 + (KT)) * 64 + lane)) * 16))

// compute one tile from registers FR/B0/B1 (numerics identical to R9)
#define COMPUTE(TILE, FR, B0, B1)                                             \
    {                                                                         \
        f32x16 sacc;                                                          \
        _Pragma("unroll")                                                     \
        for (int r = 0; r < 16; ++r) sacc[r] = 0.f;                           \
        sacc = __builtin_amdgcn_mfma_f32_32x32x16_bf16(                       \
            __builtin_bit_cast(bf16x8, FR), bfi, sacc, 0, 0, 0);              \
        const float* ajp = ajb + (TILE) * 32 + 4 * h;                         \
        float aqf[16] __attribute__((aligned(16)));                           \
        *(float4*)&aqf[0]  = *(const float4*)(ajp);                           \
        *(float4*)&aqf[4]  = *(const float4*)(ajp + 8);                       \
        *(float4*)&aqf[8]  = *(const float4*)(ajp + 16);                      \
        *(float4*)&aqf[12] = *(const float4*)(ajp + 24);                      \
        short wv16[16] __attribute__((aligned(16)));                          \
        _Pragma("unroll")                                                     \
        for (int r = 0; r < 16; ++r) {                                        \
            float x = (ai + aqf[r]) + sacc[r];                                \
            x = fminf(x, 0.f);                                                \
            wv16[r] = bf16s(__builtin_amdgcn_exp2f(x));                       \
        }                                                                     \
        bf16x8 a0, a1;                                                        \
        __builtin_memcpy(&a0, &wv16[0], 16);                                  \
        __builtin_memcpy(&a1, &wv16[8], 16);                                  \
        acc = __builtin_amdgcn_mfma_f32_32x32x16_bf16(                        \
            a0, __builtin_bit_cast(bf16x8, B0), acc, 0, 0, 0);                \
        acc = __builtin_amdgcn_mfma_f32_32x32x16_bf16(                        \
            a1, __builtin_bit_cast(bf16x8, B1), acc, 0, 0, 0);                \
    }

    // ---- pipelined main loop: prefetch tile s+1 before computing tile s ----
    u32x4 frA = LOADF(tile0);
    u32x4 b0A = LOADB(tile0, 0);
    u32x4 b1A = LOADB(tile0, 1);

    for (int s = 0; s < TPW; s += 2) {
        const int t1 = tile0 + s + 1;          // valid: s+1 <= TPW-1
        u32x4 frB = LOADF(t1);
        u32x4 b0B = LOADB(t1, 0);
        u32x4 b1B = LOADB(t1, 1);
        COMPUTE(tile0 + s, frA, b0A, b1A);

        const int t2 = (s + 2 <= TPW - 1) ? (tile0 + s + 2) : tmax;  // clamp
        frA = LOADF(t2);
        b0A = LOADB(t2, 0);
        b1A = LOADB(t2, 1);
        COMPUTE(t1, frB, b0B, b1B);
    }
#undef COMPUTE
#undef LOADF
#undef LOADB

    __syncthreads();   // all waves done with ajb; reuse LDS for reduce

    // ---- write partials: red[wv][row][m] ----
    #pragma unroll
    for (int r = 0; r < 16; ++r) {
        const int row = (r & 3) + 8 * (r >> 2) + 4 * h;
        red[wv * 1024 + row * 32 + m] = acc[r];
    }
    __syncthreads();

    // ---- reduce 16 waves -> out = sum - U (plain stores, no init needed) ----
    {
        const int row = t >> 5, col = t & 31;
        float s = 0.f;
        #pragma unroll
        for (int w = 0; w < NWAVE; ++w) s += red[w * 1024 + row * 32 + col];
        if (col < CC) {
            const size_t o = (size_t)(ibase + row) * CC + col;
            out[o] = s - U[o];
        }
    }
}

extern "C" void kernel_launch(void* const* d_in, const int* in_sizes, int n_in,
                              void* d_out, int out_size, void* d_ws, size_t ws_size,
                              hipStream_t stream) {
    const float* U   = (const float*)d_in[0];
    const float* ref = (const float*)d_in[1];
    float* out = (float*)d_out;
    char* ws = (char*)d_ws;   // needs 768 KB

    const int pack_threads = NTILE_G * 64 + NTILE_G * 2 * 64;   // 49152
    pack_frags<<<pack_threads / 256, 256, 0, stream>>>(U, ref, ws);
    lattice_main<<<NBLK, MAINT, 0, stream>>>(U, ref, (const char*)ws, out);
}

// Round 11
// 25.045 us; speedup vs baseline: 1.0748x; 1.0748x over previous
//
#include <hip/hip_runtime.h>
#include <hip/hip_bf16.h>

// Exact Gaussian lattice filter: out = (W - I) @ U, W_ij = exp(-0.5*max(d2,0))
// N=8192, D=5 features, C=21 channels.
//
// R11: R9/R10 verified skeleton with:
//  - aj folded into the S-MFMA (F-frag k13/k14 = aj hi/lo vs B=1.0; k15 takes
//    the d=3 lo_i cross term; only lo_i[4]*hi_j[4] dropped, err_x ~ 0.003).
//    Removes the aj LDS array, its staging phase+barrier, 4 ds_reads and 16
//    adds per tile. x = ai + sacc[r] directly; fminf dropped (x<=0+1e-4).
//  - occupancy 2x: JSPLIT=4, 512-thr blocks (8 waves), grid 1024 = 4
//    blocks/CU = 8 waves/SIMD, launch_bounds(512,8).
//  - epilogue: 8-wave LDS reduce -> unsafeAtomicAdd onto memset-zero out,
//    -U folded at jc==0. Memset is a graph node (deterministic replays).

#define NN 8192
#define CC 21
#define DD 5
#define NTILE_G (NN / 32)       // 256 j-tiles
#define ROWS 32                 // i-rows per block
#define NIB (NN / ROWS)         // 256
#define JSPLIT 4
#define TPB (NTILE_G / JSPLIT)  // 64 tiles per block
#define BLOCK 512
#define NWAVE 8
#define TPW (TPB / NWAVE)       // 8 tiles per wave

#define F_OFF 0
#define U_OFF (NTILE_G * 64 * 16)   // 262144 B

typedef __attribute__((ext_vector_type(8)))  short    bf16x8;
typedef __attribute__((ext_vector_type(16))) float    f32x16;
typedef __attribute__((ext_vector_type(4)))  unsigned u32x4;

__device__ __forceinline__ short bf16s(float x) {
    __hip_bfloat16 h = __float2bfloat16(x);   // RNE, compiler-lowered
    short s; __builtin_memcpy(&s, &h, 2); return s;
}
__device__ __forceinline__ float bf16f(short s) {
    __hip_bfloat16 h; __builtin_memcpy(&h, &s, 2); return __bfloat162float(h);
}

// ---- pack kernel: F-frags (with aj) then U-frags into ws ----
__global__ __launch_bounds__(256)
void pack_frags(const float* __restrict__ U, const float* __restrict__ ref,
                char* __restrict__ ws) {
    const float NH = -0.7213475204444817f;   // -0.5*log2(e)
    const int q = blockIdx.x * 256 + threadIdx.x;
    if (q < NTILE_G * 64) {
        // F-frag slot: tile = q>>6, frag-lane ln = q&63, j = tile*32 + (ln&31)
        const int tile = q >> 6, ln = q & 63;
        const int j = tile * 32 + (ln & 31);
        const float* fj = ref + (size_t)j * DD;
        short h_[5], l_[5];
        float sq = 0.f;
        #pragma unroll
        for (int d = 0; d < DD; ++d) {
            const float f = fj[d];
            sq = fmaf(f, f, sq);
            h_[d] = bf16s(f);
            l_[d] = bf16s(f - bf16f(h_[d]));
        }
        const float a = NH * sq;
        const short ajh = bf16s(a);
        const short ajl = bf16s(a - bf16f(ajh));
        short v[8] __attribute__((aligned(16)));
        if (ln < 32) {   // k0..7: hj0..4, lj0..2
            v[0]=h_[0]; v[1]=h_[1]; v[2]=h_[2]; v[3]=h_[3];
            v[4]=h_[4]; v[5]=l_[0]; v[6]=l_[1]; v[7]=l_[2];
        } else {         // k8..15: lj3, lj4, hj0, hj1, hj2, ajh, ajl, hj3
            v[0]=l_[3]; v[1]=l_[4]; v[2]=h_[0]; v[3]=h_[1];
            v[4]=h_[2]; v[5]=ajh;   v[6]=ajl;   v[7]=h_[3];
        }
        u32x4 pk; __builtin_memcpy(&pk, v, 16);
        *(u32x4*)(ws + F_OFF + (size_t)q * 16) = pk;
    } else {
        // U-frag slot (unchanged from R9/R10)
        const int qu = q - NTILE_G * 64;
        const int ln = qu & 63, kt = (qu >> 6) & 1, tile = qu >> 7;
        const int c = ln & 31, g = ln >> 5;
        short v[8] __attribute__((aligned(16))) = {0,0,0,0,0,0,0,0};
        if (c < CC) {
            #pragma unroll
            for (int e = 0; e < 8; ++e) {
                const int j = tile * 32 + kt * 16 + (e & 3) + 8 * (e >> 2) + 4 * g;
                v[e] = bf16s(U[(size_t)j * CC + c]);
            }
        }
        u32x4 pk; __builtin_memcpy(&pk, v, 16);
        *(u32x4*)(ws + U_OFF + (size_t)qu * 16) = pk;
    }
}

// ---- main kernel ----
__global__ __launch_bounds__(BLOCK, 8)
void lattice_main(const float* __restrict__ U, const float* __restrict__ ref,
                  const char* __restrict__ ws, float* __restrict__ out) {
    __shared__ __align__(16) float red[NWAVE * ROWS * 32];   // 32 KB

    const int t    = threadIdx.x;
    const int lane = t & 63;
    const int wv   = t >> 6;        // wave 0..7
    const int h    = lane >> 5;
    const int m    = lane & 31;
    const int ibase = blockIdx.x * ROWS;
    const int jc    = blockIdx.y;
    const float L  = 1.4426950408889634f;    // log2(e)
    const float NH = -0.7213475204444817f;   // -0.5*log2(e)

    // ---- per-lane i-row: ai (fp32) and L-scaled hi/lo B-fragment ----
    const float* fiP = ref + (size_t)(ibase + m) * DD;
    const float fi0 = fiP[0], fi1 = fiP[1], fi2 = fiP[2], fi3 = fiP[3], fi4 = fiP[4];
    const float ai = NH * (fi0*fi0 + fi1*fi1 + fi2*fi2 + fi3*fi3 + fi4*fi4);
    bf16x8 bfi;
    {
        const float sf[5] = {L*fi0, L*fi1, L*fi2, L*fi3, L*fi4};
        short hi_[5], lo_[5];
        #pragma unroll
        for (int d = 0; d < DD; ++d) {
            hi_[d] = bf16s(sf[d]);
            lo_[d] = bf16s(sf[d] - bf16f(hi_[d]));
        }
        const short one = bf16s(1.0f);
        // B_i k-slots: k0..7 (h=0): {Lh0..Lh4, Lh0, Lh1, Lh2}
        //              k8..15 (h=1): {Lh3, Lh4, Ll0, Ll1, Ll2, 1, 1, Ll3}
        short bv[8] __attribute__((aligned(16)));
        bv[0] = h ? hi_[3] : hi_[0];
        bv[1] = h ? hi_[4] : hi_[1];
        bv[2] = h ? lo_[0] : hi_[2];
        bv[3] = h ? lo_[1] : hi_[3];
        bv[4] = h ? lo_[2] : hi_[4];
        bv[5] = h ? one    : hi_[0];
        bv[6] = h ? one    : hi_[1];
        bv[7] = h ? lo_[3] : hi_[2];
        __builtin_memcpy(&bfi, bv, 16);
    }

    f32x16 acc;
    #pragma unroll
    for (int r = 0; r < 16; ++r) acc[r] = 0.f;

    const char* Fws = ws + F_OFF;
    const char* Uws = ws + U_OFF;
    const int tile0 = jc * TPB + wv * TPW;

    // ---- main loop: 8 tiles, no barriers, no LDS ----
    for (int s = 0; s < TPW; ++s) {
        const int tile = tile0 + s;
        const u32x4 fr = *(const u32x4*)(Fws + ((size_t)(tile * 64 + lane)) * 16);
        const u32x4 b0 = *(const u32x4*)(Uws + ((size_t)((tile * 2 + 0) * 64 + lane)) * 16);
        const u32x4 b1 = *(const u32x4*)(Uws + ((size_t)((tile * 2 + 1) * 64 + lane)) * 16);

        f32x16 sacc;
        #pragma unroll
        for (int r = 0; r < 16; ++r) sacc[r] = 0.f;
        sacc = __builtin_amdgcn_mfma_f32_32x32x16_bf16(
            __builtin_bit_cast(bf16x8, fr), bfi, sacc, 0, 0, 0);
        // sacc[r] = L*(fi.fj) + aj  for j_local = (r&3)+8*(r>>2)+4h, i = m

        short wv16[16] __attribute__((aligned(16)));
        #pragma unroll
        for (int r = 0; r < 16; ++r)
            wv16[r] = bf16s(__builtin_amdgcn_exp2f(ai + sacc[r]));
        bf16x8 a0, a1;
        __builtin_memcpy(&a0, &wv16[0], 16);
        __builtin_memcpy(&a1, &wv16[8], 16);

        acc = __builtin_amdgcn_mfma_f32_32x32x16_bf16(
            a0, __builtin_bit_cast(bf16x8, b0), acc, 0, 0, 0);
        acc = __builtin_amdgcn_mfma_f32_32x32x16_bf16(
            a1, __builtin_bit_cast(bf16x8, b1), acc, 0, 0, 0);
    }

    // ---- write partials: red[wv][row][m] ----
    #pragma unroll
    for (int r = 0; r < 16; ++r) {
        const int row = (r & 3) + 8 * (r >> 2) + 4 * h;
        red[wv * (ROWS * 32) + row * 32 + m] = acc[r];
    }
    __syncthreads();

    // ---- reduce 8 waves; atomicAdd to out (memset-zeroed); -U at jc==0 ----
    #pragma unroll
    for (int k = 0; k < 2; ++k) {
        const int idx = k * BLOCK + t;            // 0..1023
        const int row = idx >> 5, col = idx & 31;
        float s = 0.f;
        #pragma unroll
        for (int w = 0; w < NWAVE; ++w) s += red[w * (ROWS * 32) + row * 32 + col];
        if (col < CC) {
            const size_t o = (size_t)(ibase + row) * CC + col;
            if (jc == 0) s -= U[o];
            unsafeAtomicAdd(&out[o], s);
        }
    }
}

extern "C" void kernel_launch(void* const* d_in, const int* in_sizes, int n_in,
                              void* d_out, int out_size, void* d_ws, size_t ws_size,
                              hipStream_t stream) {
    const float* U   = (const float*)d_in[0];
    const float* ref = (const float*)d_in[1];
    float* out = (float*)d_out;
    char* ws = (char*)d_ws;   // needs 768 KB

    hipMemsetAsync(out, 0, (size_t)out_size * sizeof(float), stream);

    const int pack_threads = NTILE_G * 64 + NTILE_G * 2 * 64;   // 49152
    pack_frags<<<pack_threads / 256, 256, 0, stream>>>(U, ref, ws);

    dim3 grid(NIB, JSPLIT);
    lattice_main<<<grid, BLOCK, 0, stream>>>(U, ref, (const char*)ws, out);
}

// Round 12
// 22.387 us; speedup vs baseline: 1.2024x; 1.1187x over previous
//
#include <hip/hip_runtime.h>

// Exact Gaussian lattice filter: out = (W - I) @ U, W_ij = exp(-0.5*max(d2,0))
// N=8192, D=5 features, C=21 channels.
//
// R12: f16 MFMA variant of the verified R8-R11 skeleton, 2 graph nodes.
//  - dtype bf16 -> f16: (_Float16) casts are single v_cvt_f16_f32 (RNE);
//    10-bit mantissa -> W/U rounding error drops 8x vs bf16.
//  - S-MFMA slots: A_j = {hj0..4, lj0..4, hj0..4, aj},
//    B_i = {Lhi0..4, Lhi0..4, Llo0..4, 1.0}; S = L*(fi.fj) + aj with only
//    Llo*lj (~2^-22) dropped; x = ai + S in fp32, w = exp2(x).
//  - 2 nodes: pack (frags -> d_ws, 768 KB) + main. JSPLIT=1: block of 16
//    waves owns 32 i-rows x all 256 j-tiles; LDS reduce; PLAIN stores
//    out = sum - U (no atomics, no memset; poison-proof).

#define NN 8192
#define CC 21
#define DD 5
#define NTILE_G (NN / 32)       // 256 j-tiles
#define ROWS 32                 // i-rows per block
#define NIB (NN / ROWS)         // 256 blocks
#define MAINT 1024              // 16 waves
#define NWAVE 16
#define TPW (NTILE_G / NWAVE)   // 16 tiles per wave

#define F_OFF 0
#define U_OFF (NTILE_G * 64 * 16)   // 262144 B

typedef __attribute__((ext_vector_type(8)))  _Float16 f16x8;
typedef __attribute__((ext_vector_type(16))) float    f32x16;
typedef __attribute__((ext_vector_type(4)))  unsigned u32x4;

// ---- pack kernel: F-frags (hi/lo + aj) then U-frags into ws ----
__global__ __launch_bounds__(256)
void pack_frags(const float* __restrict__ U, const float* __restrict__ ref,
                char* __restrict__ ws) {
    const float NH = -0.7213475204444817f;   // -0.5*log2(e)
    const int q = blockIdx.x * 256 + threadIdx.x;
    if (q < NTILE_G * 64) {
        // F-frag slot: tile = q>>6, frag-lane ln = q&63, j = tile*32 + (ln&31)
        const int tile = q >> 6, ln = q & 63;
        const int j = tile * 32 + (ln & 31);
        const float* fj = ref + (size_t)j * DD;
        _Float16 h_[5], l_[5];
        float sq = 0.f;
        #pragma unroll
        for (int d = 0; d < DD; ++d) {
            const float f = fj[d];
            sq = fmaf(f, f, sq);
            h_[d] = (_Float16)f;
            l_[d] = (_Float16)(f - (float)h_[d]);
        }
        const _Float16 aj = (_Float16)(NH * sq);
        _Float16 v[8] __attribute__((aligned(16)));
        if (ln < 32) {   // k0..7:  hj0..4, lj0, lj1, lj2
            v[0]=h_[0]; v[1]=h_[1]; v[2]=h_[2]; v[3]=h_[3];
            v[4]=h_[4]; v[5]=l_[0]; v[6]=l_[1]; v[7]=l_[2];
        } else {         // k8..15: lj3, lj4, hj0..4, aj
            v[0]=l_[3]; v[1]=l_[4]; v[2]=h_[0]; v[3]=h_[1];
            v[4]=h_[2]; v[5]=h_[3]; v[6]=h_[4]; v[7]=aj;
        }
        u32x4 pk; __builtin_memcpy(&pk, v, 16);
        *(u32x4*)(ws + F_OFF + (size_t)q * 16) = pk;
    } else {
        // U-frag slot (sigma map unchanged from R9-R11, now f16)
        const int qu = q - NTILE_G * 64;
        const int ln = qu & 63, kt = (qu >> 6) & 1, tile = qu >> 7;
        const int c = ln & 31, g = ln >> 5;
        _Float16 v[8] __attribute__((aligned(16))) = {0,0,0,0,0,0,0,0};
        if (c < CC) {
            #pragma unroll
            for (int e = 0; e < 8; ++e) {
                const int j = tile * 32 + kt * 16 + (e & 3) + 8 * (e >> 2) + 4 * g;
                v[e] = (_Float16)U[(size_t)j * CC + c];
            }
        }
        u32x4 pk; __builtin_memcpy(&pk, v, 16);
        *(u32x4*)(ws + U_OFF + (size_t)qu * 16) = pk;
    }
}

// ---- main kernel ----
__global__ __launch_bounds__(MAINT, 4)
void lattice_main(const float* __restrict__ U, const float* __restrict__ ref,
                  const char* __restrict__ ws, float* __restrict__ out) {
    __shared__ __align__(16) float red[NWAVE * ROWS * 32];   // 64 KB

    const int t    = threadIdx.x;
    const int lane = t & 63;
    const int wv   = t >> 6;        // wave 0..15
    const int h    = lane >> 5;
    const int m    = lane & 31;
    const int ibase = blockIdx.x * ROWS;
    const float L  = 1.4426950408889634f;    // log2(e)
    const float NH = -0.7213475204444817f;   // -0.5*log2(e)

    // ---- per-lane i-row: ai (fp32) and L-scaled hi/lo f16 B-fragment ----
    const float* fiP = ref + (size_t)(ibase + m) * DD;
    const float fi0 = fiP[0], fi1 = fiP[1], fi2 = fiP[2], fi3 = fiP[3], fi4 = fiP[4];
    const float ai = NH * (fi0*fi0 + fi1*fi1 + fi2*fi2 + fi3*fi3 + fi4*fi4);
    f16x8 bfi;
    {
        const float sf[5] = {L*fi0, L*fi1, L*fi2, L*fi3, L*fi4};
        _Float16 hi_[5], lo_[5];
        #pragma unroll
        for (int d = 0; d < DD; ++d) {
            hi_[d] = (_Float16)sf[d];
            lo_[d] = (_Float16)(sf[d] - (float)hi_[d]);
        }
        // B_i k-slots: k0..7 (h=0): {Lhi0..4, Lhi0, Lhi1, Lhi2}
        //              k8..15 (h=1): {Lhi3, Lhi4, Llo0..4, 1.0}
        _Float16 bv[8] __attribute__((aligned(16)));
        bv[0] = h ? hi_[3] : hi_[0];
        bv[1] = h ? hi_[4] : hi_[1];
        bv[2] = h ? lo_[0] : hi_[2];
        bv[3] = h ? lo_[1] : hi_[3];
        bv[4] = h ? lo_[2] : hi_[4];
        bv[5] = h ? lo_[3] : hi_[0];
        bv[6] = h ? lo_[4] : hi_[1];
        bv[7] = h ? (_Float16)1.0f : hi_[2];
        __builtin_memcpy(&bfi, bv, 16);
    }

    f32x16 acc;
    #pragma unroll
    for (int r = 0; r < 16; ++r) acc[r] = 0.f;

    const char* Fws = ws + F_OFF;
    const char* Uws = ws + U_OFF;
    const int tile0 = wv * TPW;

    // ---- main loop: 16 tiles, no barriers, no LDS ----
    for (int s = 0; s < TPW; ++s) {
        const int tile = tile0 + s;
        const u32x4 fr = *(const u32x4*)(Fws + ((size_t)(tile * 64 + lane)) * 16);
        const u32x4 b0 = *(const u32x4*)(Uws + ((size_t)((tile * 2 + 0) * 64 + lane)) * 16);
        const u32x4 b1 = *(const u32x4*)(Uws + ((size_t)((tile * 2 + 1) * 64 + lane)) * 16);

        f32x16 sacc;
        #pragma unroll
        for (int r = 0; r < 16; ++r) sacc[r] = 0.f;
        sacc = __builtin_amdgcn_mfma_f32_32x32x16_f16(
            __builtin_bit_cast(f16x8, fr), bfi, sacc, 0, 0, 0);
        // sacc[r] = L*(fi.fj) + aj  for j_local = (r&3)+8*(r>>2)+4h, i = m

        _Float16 wv16[16] __attribute__((aligned(16)));
        #pragma unroll
        for (int r = 0; r < 16; ++r)
            wv16[r] = (_Float16)__builtin_amdgcn_exp2f(ai + sacc[r]);
        f16x8 a0, a1;
        __builtin_memcpy(&a0, &wv16[0], 16);
        __builtin_memcpy(&a1, &wv16[8], 16);

        acc = __builtin_amdgcn_mfma_f32_32x32x16_f16(
            a0, __builtin_bit_cast(f16x8, b0), acc, 0, 0, 0);
        acc = __builtin_amdgcn_mfma_f32_32x32x16_f16(
            a1, __builtin_bit_cast(f16x8, b1), acc, 0, 0, 0);
    }

    // ---- write partials: red[wv][row][m] ----
    #pragma unroll
    for (int r = 0; r < 16; ++r) {
        const int row = (r & 3) + 8 * (r >> 2) + 4 * h;
        red[wv * (ROWS * 32) + row * 32 + m] = acc[r];
    }
    __syncthreads();

    // ---- reduce 16 waves -> out = sum - U (plain stores) ----
    {
        const int row = t >> 5, col = t & 31;
        float s = 0.f;
        #pragma unroll
        for (int w = 0; w < NWAVE; ++w) s += red[w * (ROWS * 32) + row * 32 + col];
        if (col < CC) {
            const size_t o = (size_t)(ibase + row) * CC + col;
            out[o] = s - U[o];
        }
    }
}

extern "C" void kernel_launch(void* const* d_in, const int* in_sizes, int n_in,
                              void* d_out, int out_size, void* d_ws, size_t ws_size,
                              hipStream_t stream) {
    const float* U   = (const float*)d_in[0];
    const float* ref = (const float*)d_in[1];
    float* out = (float*)d_out;
    char* ws = (char*)d_ws;   // needs 768 KB

    const int pack_threads = NTILE_G * 64 + NTILE_G * 2 * 64;   // 49152
    pack_frags<<<pack_threads / 256, 256, 0, stream>>>(U, ref, ws);
    lattice_main<<<NIB, MAINT, 0, stream>>>(U, ref, (const char*)ws, out);
}